// Round 5
// baseline (407.552 us; speedup 1.0000x reference)
//
#include <hip/hip_runtime.h>

#define N_OP   50000
#define N_MAC  2000
#define IN_OP  64
#define IN_MAC 32
#define OUT    128
#define HEADS  4
#define DK     32
#define ATT_DIM 65
#define E_SEQ  150000
#define E_OM   300000
#define E_MO   300000
#define TOT_E  (E_SEQ + E_MO + E_OM)
#define EPS    1e-6f
#define LN_EPS 1e-5f

#define GB_OP   1024                   // op gemm+proj blocks
#define GB_MAC  125                    // mac gemm+proj blocks (16-row tiles)
#define HB      512                    // histogram blocks (grid-stride)
#define T_OP    (N_OP / 16)            // 3125
#define CNT_B   ((TOT_E + 255) / 256)  // fill_alpha blocks

#define AB_SEQ  ((N_OP + 255) / 256)
#define AB_MO   ((N_OP + 255) / 256)
#define AB_OM   ((N_MAC + 255) / 256)

#define LDH_OP  68                     // padded LDS stride (floats) for 64-wide rows
#define LDH_MAC 36                     // padded LDS stride for 32-wide rows

typedef unsigned short ushort_t;
typedef unsigned int   uint_t;

__device__ __forceinline__ ushort_t f32_to_bf16_rtne(float f) {
    uint_t u = __float_as_uint(f);
    u += 0x7FFFu + ((u >> 16) & 1u);
    return (ushort_t)(u >> 16);
}

__device__ __forceinline__ float dot4(float4 a, float4 b) {
    return a.x * b.x + a.y * b.y + a.z * b.z + a.w * b.w;
}

// ---------------------------------------------------------------------------
// Prep: block 0 folds attention vectors through W (U = att o W, c = att o b);
// blocks >= 1 zero the count/ctr arrays (replaces hipMemsetAsync dispatch).
// U_op row j = pr*4+hd: pr0=seq_src, pr1=seq_dst, pr2=om_src, pr3=mo_dst.
// U_mac row j: pr0=om_dst(att_om[32:64]), pr1=mo_src(att_mo[0:32]).
// ---------------------------------------------------------------------------
__global__ void k_prep(const float* __restrict__ W_op, const float* __restrict__ b_op,
                       const float* __restrict__ W_mac, const float* __restrict__ b_mac,
                       const float* __restrict__ att_seq, const float* __restrict__ att_om,
                       const float* __restrict__ att_mo,
                       float* __restrict__ U_op, float* __restrict__ c_op,
                       float* __restrict__ U_mac, float* __restrict__ c_mac,
                       int* __restrict__ zero_base) {
    const int t = threadIdx.x;
    if (blockIdx.x == 0) {
        for (int idx = t; idx < 16 * IN_OP; idx += 256) {
            const int j = idx >> 6, k = idx & 63;
            const int hd = j & 3, pr = j >> 2;
            const float* att = (pr <= 1) ? att_seq : (pr == 2 ? att_om : att_mo);
            const int off = (pr == 1 || pr == 3) ? 32 : 0;
            float s = 0.f;
            for (int l = 0; l < 32; ++l)
                s += att[hd * ATT_DIM + off + l] * W_op[(hd * 32 + l) * IN_OP + k];
            U_op[idx] = s;
        }
        if (t < 16) {
            const int hd = t & 3, pr = t >> 2;
            const float* att = (pr <= 1) ? att_seq : (pr == 2 ? att_om : att_mo);
            const int off = (pr == 1 || pr == 3) ? 32 : 0;
            float s = 0.f;
            for (int l = 0; l < 32; ++l) s += att[hd * ATT_DIM + off + l] * b_op[hd * 32 + l];
            c_op[t] = s;
        }
        for (int idx = t; idx < 8 * IN_MAC; idx += 256) {
            const int j = idx >> 5, k = idx & 31;
            const int hd = j & 3, pr = j >> 2;
            const float* att = (pr == 0) ? att_om : att_mo;
            const int off = (pr == 0) ? 32 : 0;
            float s = 0.f;
            for (int l = 0; l < 32; ++l)
                s += att[hd * ATT_DIM + off + l] * W_mac[(hd * 32 + l) * IN_MAC + k];
            U_mac[idx] = s;
        }
        if (t < 8) {
            const int hd = t & 3, pr = t >> 2;
            const float* att = (pr == 0) ? att_om : att_mo;
            const int off = (pr == 0) ? 32 : 0;
            float s = 0.f;
            for (int l = 0; l < 32; ++l) s += att[hd * ATT_DIM + off + l] * b_mac[hd * 32 + l];
            c_mac[t] = s;
        }
    } else {
        const int n = 2 * N_OP + N_MAC + 4;
        for (int i = (blockIdx.x - 1) * 256 + t; i < n; i += 63 * 256)
            zero_base[i] = 0;
    }
}

// ---------------------------------------------------------------------------
// Phase 1: [A] op GEMM (2 cols x 4 rows per thread) + fused projections |
// [B] mac GEMM + projections | [E] degree histograms (grid-stride).
// LDS padded stride-68/36 => conflict-free; staging as strided dwords.
// ---------------------------------------------------------------------------
__global__ void k_phase1(
    const float* __restrict__ h_op, const float* __restrict__ W_op, const float* __restrict__ b_op,
    const float* __restrict__ h_mac, const float* __restrict__ W_mac, const float* __restrict__ b_mac,
    const float* __restrict__ U_op, const float* __restrict__ c_op,
    const float* __restrict__ U_mac, const float* __restrict__ c_mac,
    float* __restrict__ z_op, ushort_t* __restrict__ zb_op,
    float* __restrict__ z_mac, ushort_t* __restrict__ zb_mac,
    float* __restrict__ p_op, float* __restrict__ p_mac,
    const int* __restrict__ seq_dst, const int* __restrict__ mo_dst, const int* __restrict__ om_dst,
    int* __restrict__ cnt_seq, int* __restrict__ cnt_mo, int* __restrict__ cnt_om) {
    const int bid = blockIdx.x;
    const int t = threadIdx.x;
    __shared__ float hS[16 * LDH_OP];
    __shared__ float uS[16 * LDH_OP];
    __shared__ float cS[16];

    if (bid < GB_OP) {
        // ---- [A] op GEMM: thread owns cols (2cp, 2cp+1), rows slot*4..+3 ----
        const int cp = t & 63, slot = t >> 6;
        const int c0 = cp * 2;
        float4 w0[16], w1[16];
        {
            const float4* Wv0 = reinterpret_cast<const float4*>(W_op + c0 * IN_OP);
            const float4* Wv1 = reinterpret_cast<const float4*>(W_op + (c0 + 1) * IN_OP);
#pragma unroll
            for (int k = 0; k < 16; ++k) { w0[k] = Wv0[k]; w1[k] = Wv1[k]; }
        }
        const float bia0 = b_op[c0], bia1 = b_op[c0 + 1];
        // stage U (padded) once
        for (int i = t; i < 16 * IN_OP; i += 256) uS[(i >> 6) * LDH_OP + (i & 63)] = U_op[i];
        if (t < 16) cS[t] = c_op[t];
        const int pr = t >> 4, pj = t & 15;
        const float4* uv = reinterpret_cast<const float4*>(&uS[pj * LDH_OP]);
        const float4* hp = reinterpret_cast<const float4*>(&hS[pr * LDH_OP]);
        const float4* h0 = reinterpret_cast<const float4*>(&hS[(slot * 4 + 0) * LDH_OP]);
        const float4* h1 = reinterpret_cast<const float4*>(&hS[(slot * 4 + 1) * LDH_OP]);
        const float4* h2 = reinterpret_cast<const float4*>(&hS[(slot * 4 + 2) * LDH_OP]);
        const float4* h3 = reinterpret_cast<const float4*>(&hS[(slot * 4 + 3) * LDH_OP]);

        for (int tile = bid; tile < T_OP; tile += GB_OP) {
            const int row0 = tile * 16;
            __syncthreads();
#pragma unroll
            for (int i = 0; i < 4; ++i) {
                const int idx = t + i * 256;
                hS[(idx >> 6) * LDH_OP + (idx & 63)] = h_op[(size_t)row0 * IN_OP + idx];
            }
            __syncthreads();
            float z00 = bia0, z01 = bia1, z10 = bia0, z11 = bia1;
            float z20 = bia0, z21 = bia1, z30 = bia0, z31 = bia1;
#pragma unroll
            for (int k = 0; k < 16; ++k) {
                const float4 a0 = w0[k], a1 = w1[k];
                float4 hh;
                hh = h0[k]; z00 += dot4(a0, hh); z01 += dot4(a1, hh);
                hh = h1[k]; z10 += dot4(a0, hh); z11 += dot4(a1, hh);
                hh = h2[k]; z20 += dot4(a0, hh); z21 += dot4(a1, hh);
                hh = h3[k]; z30 += dot4(a0, hh); z31 += dot4(a1, hh);
            }
            const int r0 = row0 + slot * 4;
            {
                float zz0[4] = {z00, z10, z20, z30};
                float zz1[4] = {z01, z11, z21, z31};
#pragma unroll
                for (int r = 0; r < 4; ++r) {
                    const size_t o = (size_t)(r0 + r) * OUT + c0;
                    *reinterpret_cast<float2*>(z_op + o) = make_float2(zz0[r], zz1[r]);
                    const uint_t pk = (uint_t)f32_to_bf16_rtne(zz0[r]) |
                                      ((uint_t)f32_to_bf16_rtne(zz1[r]) << 16);
                    *reinterpret_cast<uint_t*>(zb_op + o) = pk;
                }
            }
            // fused projection: thread (pr,pj) -> p_op[row0+pr][pj]
            float ap = cS[pj];
#pragma unroll
            for (int k = 0; k < 16; ++k) ap += dot4(uv[k], hp[k]);
            p_op[(size_t)(row0 + pr) * 16 + pj] = ap;
        }
    } else if (bid < GB_OP + GB_MAC) {
        // ---- [B] mac GEMM + projections (single 16-row tile) ----
        const int row0 = (bid - GB_OP) * 16;
        const int cp = t & 63, slot = t >> 6;
        const int c0 = cp * 2;
        float4 w0[8], w1[8];
        {
            const float4* Wv0 = reinterpret_cast<const float4*>(W_mac + c0 * IN_MAC);
            const float4* Wv1 = reinterpret_cast<const float4*>(W_mac + (c0 + 1) * IN_MAC);
#pragma unroll
            for (int k = 0; k < 8; ++k) { w0[k] = Wv0[k]; w1[k] = Wv1[k]; }
        }
        const float bia0 = b_mac[c0], bia1 = b_mac[c0 + 1];
        for (int i = t; i < 8 * IN_MAC; i += 256) uS[(i >> 5) * LDH_MAC + (i & 31)] = U_mac[i];
        if (t < 8) cS[t] = c_mac[t];
#pragma unroll
        for (int i = 0; i < 2; ++i) {
            const int idx = t + i * 256;
            hS[(idx >> 5) * LDH_MAC + (idx & 31)] = h_mac[(size_t)row0 * IN_MAC + idx];
        }
        __syncthreads();
        const float4* h0 = reinterpret_cast<const float4*>(&hS[(slot * 4 + 0) * LDH_MAC]);
        const float4* h1 = reinterpret_cast<const float4*>(&hS[(slot * 4 + 1) * LDH_MAC]);
        const float4* h2 = reinterpret_cast<const float4*>(&hS[(slot * 4 + 2) * LDH_MAC]);
        const float4* h3 = reinterpret_cast<const float4*>(&hS[(slot * 4 + 3) * LDH_MAC]);
        float z00 = bia0, z01 = bia1, z10 = bia0, z11 = bia1;
        float z20 = bia0, z21 = bia1, z30 = bia0, z31 = bia1;
#pragma unroll
        for (int k = 0; k < 8; ++k) {
            const float4 a0 = w0[k], a1 = w1[k];
            float4 hh;
            hh = h0[k]; z00 += dot4(a0, hh); z01 += dot4(a1, hh);
            hh = h1[k]; z10 += dot4(a0, hh); z11 += dot4(a1, hh);
            hh = h2[k]; z20 += dot4(a0, hh); z21 += dot4(a1, hh);
            hh = h3[k]; z30 += dot4(a0, hh); z31 += dot4(a1, hh);
        }
        const int r0 = row0 + slot * 4;
        {
            float zz0[4] = {z00, z10, z20, z30};
            float zz1[4] = {z01, z11, z21, z31};
#pragma unroll
            for (int r = 0; r < 4; ++r) {
                const size_t o = (size_t)(r0 + r) * OUT + c0;
                *reinterpret_cast<float2*>(z_mac + o) = make_float2(zz0[r], zz1[r]);
                const uint_t pk = (uint_t)f32_to_bf16_rtne(zz0[r]) |
                                  ((uint_t)f32_to_bf16_rtne(zz1[r]) << 16);
                *reinterpret_cast<uint_t*>(zb_mac + o) = pk;
            }
        }
        if (t < 128) {
            const int pr = t >> 3, pj = t & 7;
            const float4* uv = reinterpret_cast<const float4*>(&uS[pj * LDH_MAC]);
            const float4* hp = reinterpret_cast<const float4*>(&hS[pr * LDH_MAC]);
            float ap = cS[pj];
#pragma unroll
            for (int k = 0; k < 8; ++k) ap += dot4(uv[k], hp[k]);
            p_mac[(size_t)(row0 + pr) * 8 + pj] = ap;
        }
    } else {
        // ---- [E] degree histograms, grid-stride ----
        const int b2 = bid - GB_OP - GB_MAC;
        for (int ge = b2 * 256 + t; ge < TOT_E; ge += HB * 256) {
            if (ge < E_SEQ) atomicAdd(&cnt_seq[seq_dst[ge]], 1);
            else if (ge < E_SEQ + E_MO) atomicAdd(&cnt_mo[mo_dst[ge - E_SEQ]], 1);
            else atomicAdd(&cnt_om[om_dst[ge - E_SEQ - E_MO]], 1);
        }
    }
}

// ---------------------------------------------------------------------------
// Range allocation: per-wave scan of counts + one atomicAdd per wave.
// ---------------------------------------------------------------------------
__global__ void k_alloc(const int* __restrict__ cnt_seq, int* __restrict__ sta_seq, int* __restrict__ off_seq,
                        const int* __restrict__ cnt_mo,  int* __restrict__ sta_mo,  int* __restrict__ off_mo,
                        const int* __restrict__ cnt_om,  int* __restrict__ sta_om,  int* __restrict__ off_om,
                        int* __restrict__ ctr) {
    const int b = blockIdx.x, t = threadIdx.x;
    const int* cnt; int* sta; int* off; int n, g, lb;
    if (b < AB_SEQ)             { cnt = cnt_seq; sta = sta_seq; off = off_seq; n = N_OP;  g = 0; lb = b; }
    else if (b < AB_SEQ + AB_MO){ cnt = cnt_mo;  sta = sta_mo;  off = off_mo;  n = N_OP;  g = 1; lb = b - AB_SEQ; }
    else                        { cnt = cnt_om;  sta = sta_om;  off = off_om;  n = N_MAC; g = 2; lb = b - AB_SEQ - AB_MO; }
    const int d = lb * 256 + t;
    const int lane = t & 63;
    const int v = (d < n) ? cnt[d] : 0;
    int x = v;
#pragma unroll
    for (int m = 1; m < 64; m <<= 1) {
        int y = __shfl_up(x, m);
        if (lane >= m) x += y;
    }
    int base = 0;
    if (lane == 63) base = atomicAdd(&ctr[g], x);
    base = __shfl(base, 63);
    if (d < n) {
        const int s = base + x - v;
        sta[d] = s;
        off[d] = s;
    }
}

// ---------------------------------------------------------------------------
// Fill + alpha (all 3 graphs), written in bucket order.
// ---------------------------------------------------------------------------
__global__ void k_fill_alpha(
    const int* __restrict__ seq_src, const int* __restrict__ seq_dst, const float* __restrict__ feat_seq,
    const int* __restrict__ mo_src,  const int* __restrict__ mo_dst,  const float* __restrict__ feat_mo,
    const int* __restrict__ om_src,  const int* __restrict__ om_dst,  const float* __restrict__ feat_om,
    const float* __restrict__ p_op, const float* __restrict__ p_mac,
    const float* __restrict__ att_seq, const float* __restrict__ att_mo, const float* __restrict__ att_om,
    int* __restrict__ off_seq, int* __restrict__ off_mo, int* __restrict__ off_om,
    float* __restrict__ al_seq, float* __restrict__ al_mo, float* __restrict__ al_om,
    int* __restrict__ bs_seq, int* __restrict__ bs_mo, int* __restrict__ bs_om) {
    const int ge = blockIdx.x * 256 + threadIdx.x;
    if (ge >= TOT_E) return;
    int s, d, pos;
    float f;
    float4 as, ad, aw;
    int* bs; float* abkt;
    if (ge < E_SEQ) {
        const int e = ge;
        s = seq_src[e]; d = seq_dst[e]; f = feat_seq[e];
        as = *reinterpret_cast<const float4*>(p_op + (size_t)s * 16 + 0);
        ad = *reinterpret_cast<const float4*>(p_op + (size_t)d * 16 + 4);
        aw = make_float4(att_seq[64], att_seq[ATT_DIM + 64], att_seq[2 * ATT_DIM + 64], att_seq[3 * ATT_DIM + 64]);
        pos = atomicAdd(&off_seq[d], 1);
        abkt = al_seq; bs = bs_seq;
    } else if (ge < E_SEQ + E_MO) {
        const int e = ge - E_SEQ;
        s = mo_src[e]; d = mo_dst[e]; f = feat_mo[e];
        as = *reinterpret_cast<const float4*>(p_mac + (size_t)s * 8 + 4);
        ad = *reinterpret_cast<const float4*>(p_op + (size_t)d * 16 + 12);
        aw = make_float4(att_mo[64], att_mo[ATT_DIM + 64], att_mo[2 * ATT_DIM + 64], att_mo[3 * ATT_DIM + 64]);
        pos = atomicAdd(&off_mo[d], 1);
        abkt = al_mo; bs = bs_mo;
    } else {
        const int e = ge - E_SEQ - E_MO;
        s = om_src[e]; d = om_dst[e]; f = feat_om[e];
        as = *reinterpret_cast<const float4*>(p_op + (size_t)s * 16 + 8);
        ad = *reinterpret_cast<const float4*>(p_mac + (size_t)d * 8 + 0);
        aw = make_float4(att_om[64], att_om[ATT_DIM + 64], att_om[2 * ATT_DIM + 64], att_om[3 * ATT_DIM + 64]);
        pos = atomicAdd(&off_om[d], 1);
        abkt = al_om; bs = bs_om;
    }
    const float sc[4] = {as.x + ad.x + f * aw.x, as.y + ad.y + f * aw.y,
                         as.z + ad.z + f * aw.z, as.w + ad.w + f * aw.w};
    float4 out;
    float* o = &out.x;
#pragma unroll
    for (int hh = 0; hh < 4; ++hh) {
        float v = sc[hh];
        v = (v >= 0.f) ? v : 0.2f * v;
        v = fminf(fmaxf(v, -20.f), 20.f);
        o[hh] = expf(v);
    }
    *reinterpret_cast<float4*>(abkt + (size_t)pos * HEADS) = out;
    bs[pos] = s;
}

// ---------------------------------------------------------------------------
// Gather. mac rows: one BLOCK per row (4 waves stride the ~150 edges, LDS
// combine, wave 0 finalizes). op rows: one WAVE per row (seq + mo segments).
// 2 cols per lane, bf16 z gathers, wave LN + ELU.
// ---------------------------------------------------------------------------
__device__ __forceinline__ void seg2(const int* __restrict__ bs, const float* __restrict__ al,
                                     const ushort_t* __restrict__ zb,
                                     int s0, int e0, int stride, int lane, int hd, int col2,
                                     float& num0, float& num1, float& den) {
    for (int base = s0; base < e0; base += stride) {
        int nn = e0 - base;
        if (nn > 64) nn = 64;
        int sidx = 0;
        if (base + lane < e0) sidx = bs[base + lane];
#pragma unroll 8
        for (int i = 0; i < nn; ++i) {
            const int s = __shfl(sidx, i);
            const float a = al[(size_t)(base + i) * HEADS + hd];
            const uint_t zz = *reinterpret_cast<const uint_t*>(zb + (size_t)s * OUT + col2);
            num0 = fmaf(a, __uint_as_float(zz << 16), num0);
            num1 = fmaf(a, __uint_as_float(zz & 0xffff0000u), num1);
            den += a;
        }
    }
}

__device__ __forceinline__ float2 ln_elu2(float x0, float x1, int lane,
                                          const float* __restrict__ g,
                                          const float* __restrict__ bb, int col2) {
    float s = x0 + x1;
#pragma unroll
    for (int m = 32; m >= 1; m >>= 1) s += __shfl_xor(s, m);
    const float mu = s * (1.0f / OUT);
    const float dx0 = x0 - mu, dx1 = x1 - mu;
    float q = dx0 * dx0 + dx1 * dx1;
#pragma unroll
    for (int m = 32; m >= 1; m >>= 1) q += __shfl_xor(q, m);
    const float r = rsqrtf(q * (1.0f / OUT) + LN_EPS);
    const float2 g2 = *reinterpret_cast<const float2*>(g + col2);
    const float2 b2 = *reinterpret_cast<const float2*>(bb + col2);
    float y0 = dx0 * r * g2.x + b2.x;
    float y1 = dx1 * r * g2.y + b2.y;
    y0 = (y0 > 0.f) ? y0 : expm1f(y0);
    y1 = (y1 > 0.f) ? y1 : expm1f(y1);
    return make_float2(y0, y1);
}

__global__ void k_gather(
    const int* __restrict__ bs_seq, const float* __restrict__ al_seq,
    const int* __restrict__ sta_seq, const int* __restrict__ off_seq,
    const int* __restrict__ bs_mo, const float* __restrict__ al_mo,
    const int* __restrict__ sta_mo, const int* __restrict__ off_mo,
    const int* __restrict__ bs_om, const float* __restrict__ al_om,
    const int* __restrict__ sta_om, const int* __restrict__ off_om,
    const ushort_t* __restrict__ zb_op, const ushort_t* __restrict__ zb_mac,
    const float* __restrict__ z_op, const float* __restrict__ z_mac,
    const float* __restrict__ g_op, const float* __restrict__ b_op,
    const float* __restrict__ g_mac, const float* __restrict__ b_mac,
    float* __restrict__ out_op, float* __restrict__ out_mac) {
    const int bid = blockIdx.x;
    const int t = threadIdx.x;
    const int w = t >> 6, lane = t & 63;
    const int hd = lane >> 4;
    const int col2 = lane * 2;
    __shared__ float nsh[4][OUT];
    __shared__ float dsh[4][HEADS];

    if (bid < N_MAC) {
        const int d = bid;
        const int s0 = sta_om[d], e0 = off_om[d];
        float num0 = 0.f, num1 = 0.f, den = 0.f;
        seg2(bs_om, al_om, zb_op, s0 + w * 64, e0, 256, lane, hd, col2, num0, num1, den);
        nsh[w][col2] = num0;
        nsh[w][col2 + 1] = num1;
        if ((lane & 15) == 0) dsh[w][hd] = den;
        __syncthreads();
        if (w == 0) {
            const float n0 = nsh[0][col2] + nsh[1][col2] + nsh[2][col2] + nsh[3][col2];
            const float n1 = nsh[0][col2 + 1] + nsh[1][col2 + 1] + nsh[2][col2 + 1] + nsh[3][col2 + 1];
            const float dt = dsh[0][hd] + dsh[1][hd] + dsh[2][hd] + dsh[3][hd];
            const float inv = 1.0f / (dt + EPS);
            const float2 zr = *reinterpret_cast<const float2*>(z_mac + (size_t)d * OUT + col2);
            const float2 o2 = ln_elu2(n0 * inv + zr.x, n1 * inv + zr.y, lane, g_mac, b_mac, col2);
            *reinterpret_cast<float2*>(out_mac + (size_t)d * OUT + col2) = o2;
        }
    } else {
        const int d = (bid - N_MAC) * 4 + w;
        if (d >= N_OP) return;
        float acc0 = 0.f, acc1 = 0.f;
        {
            float num0 = 0.f, num1 = 0.f, den = 0.f;
            seg2(bs_seq, al_seq, zb_op, sta_seq[d], off_seq[d], 64, lane, hd, col2, num0, num1, den);
            const float inv = 1.0f / (den + EPS);
            acc0 = num0 * inv; acc1 = num1 * inv;
        }
        {
            float num0 = 0.f, num1 = 0.f, den = 0.f;
            seg2(bs_mo, al_mo, zb_mac, sta_mo[d], off_mo[d], 64, lane, hd, col2, num0, num1, den);
            const float inv = 1.0f / (den + EPS);
            acc0 += num0 * inv; acc1 += num1 * inv;
        }
        const float2 zr = *reinterpret_cast<const float2*>(z_op + (size_t)d * OUT + col2);
        const float2 o2 = ln_elu2(acc0 + zr.x, acc1 + zr.y, lane, g_op, b_op, col2);
        *reinterpret_cast<float2*>(out_op + (size_t)d * OUT + col2) = o2;
    }
}

extern "C" void kernel_launch(void* const* d_in, const int* in_sizes, int n_in,
                              void* d_out, int out_size, void* d_ws, size_t ws_size,
                              hipStream_t stream) {
    const float* h_op      = (const float*)d_in[0];
    const float* h_mac     = (const float*)d_in[1];
    const int*   seq_src   = (const int*)d_in[2];
    const int*   seq_dst   = (const int*)d_in[3];
    const int*   om_src    = (const int*)d_in[4];
    const int*   om_dst    = (const int*)d_in[5];
    const int*   mo_src    = (const int*)d_in[6];
    const int*   mo_dst    = (const int*)d_in[7];
    const float* feat_seq  = (const float*)d_in[8];
    const float* feat_om   = (const float*)d_in[9];
    const float* feat_mo   = (const float*)d_in[10];
    const float* W_op_w    = (const float*)d_in[11];
    const float* W_op_b    = (const float*)d_in[12];
    const float* W_mac_w   = (const float*)d_in[13];
    const float* W_mac_b   = (const float*)d_in[14];
    const float* att_seq   = (const float*)d_in[15];
    const float* att_om    = (const float*)d_in[16];
    const float* att_mo    = (const float*)d_in[17];
    const float* ln_op_g   = (const float*)d_in[18];
    const float* ln_op_b   = (const float*)d_in[19];
    const float* ln_mac_g  = (const float*)d_in[20];
    const float* ln_mac_b  = (const float*)d_in[21];

    float* p = (float*)d_ws;
    float* z_op   = p; p += (size_t)N_OP * OUT;
    float* z_mac  = p; p += (size_t)N_MAC * OUT;
    float* p_op   = p; p += (size_t)N_OP * 16;
    float* p_mac  = p; p += (size_t)N_MAC * 8;
    float* al_seq = p; p += (size_t)E_SEQ * HEADS;
    float* al_mo  = p; p += (size_t)E_MO * HEADS;
    float* al_om  = p; p += (size_t)E_OM * HEADS;
    float* U_op   = p; p += 16 * IN_OP;
    float* c_op   = p; p += 16;
    float* U_mac  = p; p += 8 * IN_MAC;
    float* c_mac  = p; p += 16;
    ushort_t* zb_op  = (ushort_t*)p; p += (size_t)N_OP * OUT / 2;
    ushort_t* zb_mac = (ushort_t*)p; p += (size_t)N_MAC * OUT / 2;
    int* q = (int*)p;
    int* cnt_seq = q; q += N_OP;    // cnt_* + ctr contiguous, zeroed in k_prep
    int* cnt_mo  = q; q += N_OP;
    int* cnt_om  = q; q += N_MAC;
    int* ctr     = q; q += 4;
    int* sta_seq = q; q += N_OP;
    int* sta_mo  = q; q += N_OP;
    int* sta_om  = q; q += N_MAC;
    int* off_seq = q; q += N_OP;
    int* off_mo  = q; q += N_OP;
    int* off_om  = q; q += N_MAC;
    int* bs_seq  = q; q += E_SEQ;
    int* bs_mo   = q; q += E_MO;
    int* bs_om   = q; q += E_OM;

    float* out_op  = (float*)d_out;
    float* out_mac = (float*)d_out + (size_t)N_OP * OUT;

    k_prep<<<64, 256, 0, stream>>>(W_op_w, W_op_b, W_mac_w, W_mac_b,
                                   att_seq, att_om, att_mo,
                                   U_op, c_op, U_mac, c_mac, cnt_seq);

    k_phase1<<<GB_OP + GB_MAC + HB, 256, 0, stream>>>(
        h_op, W_op_w, W_op_b, h_mac, W_mac_w, W_mac_b,
        U_op, c_op, U_mac, c_mac,
        z_op, zb_op, z_mac, zb_mac, p_op, p_mac,
        seq_dst, mo_dst, om_dst, cnt_seq, cnt_mo, cnt_om);

    k_alloc<<<AB_SEQ + AB_MO + AB_OM, 256, 0, stream>>>(
        cnt_seq, sta_seq, off_seq, cnt_mo, sta_mo, off_mo, cnt_om, sta_om, off_om, ctr);

    k_fill_alpha<<<CNT_B, 256, 0, stream>>>(
        seq_src, seq_dst, feat_seq, mo_src, mo_dst, feat_mo, om_src, om_dst, feat_om,
        p_op, p_mac, att_seq, att_mo, att_om,
        off_seq, off_mo, off_om,
        al_seq, al_mo, al_om, bs_seq, bs_mo, bs_om);

    k_gather<<<N_MAC + (N_OP + 3) / 4, 256, 0, stream>>>(
        bs_seq, al_seq, sta_seq, off_seq,
        bs_mo, al_mo, sta_mo, off_mo,
        bs_om, al_om, sta_om, off_om,
        zb_op, zb_mac, z_op, z_mac,
        ln_op_g, ln_op_b, ln_mac_g, ln_mac_b,
        out_op, out_mac);
}

// Round 6
// 248.737 us; speedup vs baseline: 1.6385x; 1.6385x over previous
//
#include <hip/hip_runtime.h>

#define N_OP   50000
#define N_MAC  2000
#define IN_OP  64
#define IN_MAC 32
#define OUT    128
#define HEADS  4
#define DK     32
#define ATT_DIM 65
#define E_SEQ  150000
#define E_OM   300000
#define E_MO   300000
#define TOT_E  (E_SEQ + E_MO + E_OM)
#define EPS    1e-6f
#define LN_EPS 1e-5f

#define GB_OP   1024                   // op gemm+proj blocks
#define GB_MAC  125                    // mac gemm+proj blocks (16-row tiles)
#define HB      512                    // histogram blocks (grid-stride)
#define T_OP    (N_OP / 16)            // 3125
#define CNT_B   ((TOT_E + 255) / 256)  // fill_alpha blocks

#define AB_SEQ  ((N_OP + 255) / 256)
#define AB_MO   ((N_OP + 255) / 256)
#define AB_OM   ((N_MAC + 255) / 256)

#define LDH_OP  68                     // padded LDS stride (floats) for 64-wide rows
#define LDH_MAC 36                     // padded LDS stride for 32-wide rows

typedef unsigned short ushort_t;
typedef unsigned int   uint_t;

__device__ __forceinline__ ushort_t f32_to_bf16_rtne(float f) {
    uint_t u = __float_as_uint(f);
    u += 0x7FFFu + ((u >> 16) & 1u);
    return (ushort_t)(u >> 16);
}

__device__ __forceinline__ float dot4(float4 a, float4 b) {
    return a.x * b.x + a.y * b.y + a.z * b.z + a.w * b.w;
}

// ---------------------------------------------------------------------------
// Prep: block 0 folds attention vectors through W (U = att o W, c = att o b);
// blocks >= 1 zero the count/ctr arrays (replaces hipMemsetAsync dispatch).
// ---------------------------------------------------------------------------
__global__ void k_prep(const float* __restrict__ W_op, const float* __restrict__ b_op,
                       const float* __restrict__ W_mac, const float* __restrict__ b_mac,
                       const float* __restrict__ att_seq, const float* __restrict__ att_om,
                       const float* __restrict__ att_mo,
                       float* __restrict__ U_op, float* __restrict__ c_op,
                       float* __restrict__ U_mac, float* __restrict__ c_mac,
                       int* __restrict__ zero_base) {
    const int t = threadIdx.x;
    if (blockIdx.x == 0) {
        for (int idx = t; idx < 16 * IN_OP; idx += 256) {
            const int j = idx >> 6, k = idx & 63;
            const int hd = j & 3, pr = j >> 2;
            const float* att = (pr <= 1) ? att_seq : (pr == 2 ? att_om : att_mo);
            const int off = (pr == 1 || pr == 3) ? 32 : 0;
            float s = 0.f;
            for (int l = 0; l < 32; ++l)
                s += att[hd * ATT_DIM + off + l] * W_op[(hd * 32 + l) * IN_OP + k];
            U_op[idx] = s;
        }
        if (t < 16) {
            const int hd = t & 3, pr = t >> 2;
            const float* att = (pr <= 1) ? att_seq : (pr == 2 ? att_om : att_mo);
            const int off = (pr == 1 || pr == 3) ? 32 : 0;
            float s = 0.f;
            for (int l = 0; l < 32; ++l) s += att[hd * ATT_DIM + off + l] * b_op[hd * 32 + l];
            c_op[t] = s;
        }
        for (int idx = t; idx < 8 * IN_MAC; idx += 256) {
            const int j = idx >> 5, k = idx & 31;
            const int hd = j & 3, pr = j >> 2;
            const float* att = (pr == 0) ? att_om : att_mo;
            const int off = (pr == 0) ? 32 : 0;
            float s = 0.f;
            for (int l = 0; l < 32; ++l)
                s += att[hd * ATT_DIM + off + l] * W_mac[(hd * 32 + l) * IN_MAC + k];
            U_mac[idx] = s;
        }
        if (t < 8) {
            const int hd = t & 3, pr = t >> 2;
            const float* att = (pr == 0) ? att_om : att_mo;
            const int off = (pr == 0) ? 32 : 0;
            float s = 0.f;
            for (int l = 0; l < 32; ++l) s += att[hd * ATT_DIM + off + l] * b_mac[hd * 32 + l];
            c_mac[t] = s;
        }
    } else {
        const int n = 2 * N_OP + N_MAC + 4;
        for (int i = (blockIdx.x - 1) * 256 + t; i < n; i += 63 * 256)
            zero_base[i] = 0;
    }
}

// ---------------------------------------------------------------------------
// Phase 1: [A] op GEMM (2 cols x 4 rows per thread, W in regs) + fused
// projections | [B] mac GEMM + projections | [E] histograms (grid-stride).
// __launch_bounds__(256,2): VGPR cap 256 so the 128-reg W block does NOT
// spill (R5 regression: default cap 64 -> 400 MB scratch traffic).
// ---------------------------------------------------------------------------
__global__ void __launch_bounds__(256, 2) k_phase1(
    const float* __restrict__ h_op, const float* __restrict__ W_op, const float* __restrict__ b_op,
    const float* __restrict__ h_mac, const float* __restrict__ W_mac, const float* __restrict__ b_mac,
    const float* __restrict__ U_op, const float* __restrict__ c_op,
    const float* __restrict__ U_mac, const float* __restrict__ c_mac,
    float* __restrict__ z_op, ushort_t* __restrict__ zb_op,
    float* __restrict__ z_mac, ushort_t* __restrict__ zb_mac,
    float* __restrict__ p_op, float* __restrict__ p_mac,
    const int* __restrict__ seq_dst, const int* __restrict__ mo_dst, const int* __restrict__ om_dst,
    int* __restrict__ cnt_seq, int* __restrict__ cnt_mo, int* __restrict__ cnt_om) {
    const int bid = blockIdx.x;
    const int t = threadIdx.x;
    __shared__ float hS[16 * LDH_OP];
    __shared__ float uS[16 * LDH_OP];
    __shared__ float cS[16];

    if (bid < GB_OP) {
        // ---- [A] op GEMM: thread owns cols (2cp, 2cp+1), rows slot*4..+3 ----
        const int cp = t & 63, slot = t >> 6;
        const int c0 = cp * 2;
        float4 w0[16], w1[16];
        {
            const float4* Wv0 = reinterpret_cast<const float4*>(W_op + c0 * IN_OP);
            const float4* Wv1 = reinterpret_cast<const float4*>(W_op + (c0 + 1) * IN_OP);
#pragma unroll
            for (int k = 0; k < 16; ++k) { w0[k] = Wv0[k]; w1[k] = Wv1[k]; }
        }
        const float bia0 = b_op[c0], bia1 = b_op[c0 + 1];
        // stage U (padded) once
        for (int i = t; i < 16 * IN_OP; i += 256) uS[(i >> 6) * LDH_OP + (i & 63)] = U_op[i];
        if (t < 16) cS[t] = c_op[t];
        const int pr = t >> 4, pj = t & 15;
        const float4* uv = reinterpret_cast<const float4*>(&uS[pj * LDH_OP]);
        const float4* hp = reinterpret_cast<const float4*>(&hS[pr * LDH_OP]);
        const float4* h0 = reinterpret_cast<const float4*>(&hS[(slot * 4 + 0) * LDH_OP]);
        const float4* h1 = reinterpret_cast<const float4*>(&hS[(slot * 4 + 1) * LDH_OP]);
        const float4* h2 = reinterpret_cast<const float4*>(&hS[(slot * 4 + 2) * LDH_OP]);
        const float4* h3 = reinterpret_cast<const float4*>(&hS[(slot * 4 + 3) * LDH_OP]);

        for (int tile = bid; tile < T_OP; tile += GB_OP) {
            const int row0 = tile * 16;
            __syncthreads();
#pragma unroll
            for (int i = 0; i < 4; ++i) {
                const int idx = t + i * 256;
                hS[(idx >> 6) * LDH_OP + (idx & 63)] = h_op[(size_t)row0 * IN_OP + idx];
            }
            __syncthreads();
            float z00 = bia0, z01 = bia1, z10 = bia0, z11 = bia1;
            float z20 = bia0, z21 = bia1, z30 = bia0, z31 = bia1;
#pragma unroll
            for (int k = 0; k < 16; ++k) {
                const float4 a0 = w0[k], a1 = w1[k];
                float4 hh;
                hh = h0[k]; z00 += dot4(a0, hh); z01 += dot4(a1, hh);
                hh = h1[k]; z10 += dot4(a0, hh); z11 += dot4(a1, hh);
                hh = h2[k]; z20 += dot4(a0, hh); z21 += dot4(a1, hh);
                hh = h3[k]; z30 += dot4(a0, hh); z31 += dot4(a1, hh);
            }
            const int r0 = row0 + slot * 4;
            {
                float zz0[4] = {z00, z10, z20, z30};
                float zz1[4] = {z01, z11, z21, z31};
#pragma unroll
                for (int r = 0; r < 4; ++r) {
                    const size_t o = (size_t)(r0 + r) * OUT + c0;
                    *reinterpret_cast<float2*>(z_op + o) = make_float2(zz0[r], zz1[r]);
                    const uint_t pk = (uint_t)f32_to_bf16_rtne(zz0[r]) |
                                      ((uint_t)f32_to_bf16_rtne(zz1[r]) << 16);
                    *reinterpret_cast<uint_t*>(zb_op + o) = pk;
                }
            }
            // fused projection: thread (pr,pj) -> p_op[row0+pr][pj]
            float ap = cS[pj];
#pragma unroll
            for (int k = 0; k < 16; ++k) ap += dot4(uv[k], hp[k]);
            p_op[(size_t)(row0 + pr) * 16 + pj] = ap;
        }
    } else if (bid < GB_OP + GB_MAC) {
        // ---- [B] mac GEMM + projections (single 16-row tile) ----
        const int row0 = (bid - GB_OP) * 16;
        const int cp = t & 63, slot = t >> 6;
        const int c0 = cp * 2;
        float4 w0[8], w1[8];
        {
            const float4* Wv0 = reinterpret_cast<const float4*>(W_mac + c0 * IN_MAC);
            const float4* Wv1 = reinterpret_cast<const float4*>(W_mac + (c0 + 1) * IN_MAC);
#pragma unroll
            for (int k = 0; k < 8; ++k) { w0[k] = Wv0[k]; w1[k] = Wv1[k]; }
        }
        const float bia0 = b_mac[c0], bia1 = b_mac[c0 + 1];
        for (int i = t; i < 8 * IN_MAC; i += 256) uS[(i >> 5) * LDH_MAC + (i & 31)] = U_mac[i];
        if (t < 8) cS[t] = c_mac[t];
#pragma unroll
        for (int i = 0; i < 2; ++i) {
            const int idx = t + i * 256;
            hS[(idx >> 5) * LDH_MAC + (idx & 31)] = h_mac[(size_t)row0 * IN_MAC + idx];
        }
        __syncthreads();
        const float4* h0 = reinterpret_cast<const float4*>(&hS[(slot * 4 + 0) * LDH_MAC]);
        const float4* h1 = reinterpret_cast<const float4*>(&hS[(slot * 4 + 1) * LDH_MAC]);
        const float4* h2 = reinterpret_cast<const float4*>(&hS[(slot * 4 + 2) * LDH_MAC]);
        const float4* h3 = reinterpret_cast<const float4*>(&hS[(slot * 4 + 3) * LDH_MAC]);
        float z00 = bia0, z01 = bia1, z10 = bia0, z11 = bia1;
        float z20 = bia0, z21 = bia1, z30 = bia0, z31 = bia1;
#pragma unroll
        for (int k = 0; k < 8; ++k) {
            const float4 a0 = w0[k], a1 = w1[k];
            float4 hh;
            hh = h0[k]; z00 += dot4(a0, hh); z01 += dot4(a1, hh);
            hh = h1[k]; z10 += dot4(a0, hh); z11 += dot4(a1, hh);
            hh = h2[k]; z20 += dot4(a0, hh); z21 += dot4(a1, hh);
            hh = h3[k]; z30 += dot4(a0, hh); z31 += dot4(a1, hh);
        }
        const int r0 = row0 + slot * 4;
        {
            float zz0[4] = {z00, z10, z20, z30};
            float zz1[4] = {z01, z11, z21, z31};
#pragma unroll
            for (int r = 0; r < 4; ++r) {
                const size_t o = (size_t)(r0 + r) * OUT + c0;
                *reinterpret_cast<float2*>(z_mac + o) = make_float2(zz0[r], zz1[r]);
                const uint_t pk = (uint_t)f32_to_bf16_rtne(zz0[r]) |
                                  ((uint_t)f32_to_bf16_rtne(zz1[r]) << 16);
                *reinterpret_cast<uint_t*>(zb_mac + o) = pk;
            }
        }
        if (t < 128) {
            const int pr = t >> 3, pj = t & 7;
            const float4* uv = reinterpret_cast<const float4*>(&uS[pj * LDH_MAC]);
            const float4* hp = reinterpret_cast<const float4*>(&hS[pr * LDH_MAC]);
            float ap = cS[pj];
#pragma unroll
            for (int k = 0; k < 8; ++k) ap += dot4(uv[k], hp[k]);
            p_mac[(size_t)(row0 + pr) * 8 + pj] = ap;
        }
    } else {
        // ---- [E] degree histograms, grid-stride ----
        const int b2 = bid - GB_OP - GB_MAC;
        for (int ge = b2 * 256 + t; ge < TOT_E; ge += HB * 256) {
            if (ge < E_SEQ) atomicAdd(&cnt_seq[seq_dst[ge]], 1);
            else if (ge < E_SEQ + E_MO) atomicAdd(&cnt_mo[mo_dst[ge - E_SEQ]], 1);
            else atomicAdd(&cnt_om[om_dst[ge - E_SEQ - E_MO]], 1);
        }
    }
}

// ---------------------------------------------------------------------------
// Range allocation: per-wave scan of counts + one atomicAdd per wave.
// ---------------------------------------------------------------------------
__global__ void k_alloc(const int* __restrict__ cnt_seq, int* __restrict__ sta_seq, int* __restrict__ off_seq,
                        const int* __restrict__ cnt_mo,  int* __restrict__ sta_mo,  int* __restrict__ off_mo,
                        const int* __restrict__ cnt_om,  int* __restrict__ sta_om,  int* __restrict__ off_om,
                        int* __restrict__ ctr) {
    const int b = blockIdx.x, t = threadIdx.x;
    const int* cnt; int* sta; int* off; int n, g, lb;
    if (b < AB_SEQ)             { cnt = cnt_seq; sta = sta_seq; off = off_seq; n = N_OP;  g = 0; lb = b; }
    else if (b < AB_SEQ + AB_MO){ cnt = cnt_mo;  sta = sta_mo;  off = off_mo;  n = N_OP;  g = 1; lb = b - AB_SEQ; }
    else                        { cnt = cnt_om;  sta = sta_om;  off = off_om;  n = N_MAC; g = 2; lb = b - AB_SEQ - AB_MO; }
    const int d = lb * 256 + t;
    const int lane = t & 63;
    const int v = (d < n) ? cnt[d] : 0;
    int x = v;
#pragma unroll
    for (int m = 1; m < 64; m <<= 1) {
        int y = __shfl_up(x, m);
        if (lane >= m) x += y;
    }
    int base = 0;
    if (lane == 63) base = atomicAdd(&ctr[g], x);
    base = __shfl(base, 63);
    if (d < n) {
        const int s = base + x - v;
        sta[d] = s;
        off[d] = s;
    }
}

// ---------------------------------------------------------------------------
// Fill + alpha (all 3 graphs), written in bucket order.
// ---------------------------------------------------------------------------
__global__ void k_fill_alpha(
    const int* __restrict__ seq_src, const int* __restrict__ seq_dst, const float* __restrict__ feat_seq,
    const int* __restrict__ mo_src,  const int* __restrict__ mo_dst,  const float* __restrict__ feat_mo,
    const int* __restrict__ om_src,  const int* __restrict__ om_dst,  const float* __restrict__ feat_om,
    const float* __restrict__ p_op, const float* __restrict__ p_mac,
    const float* __restrict__ att_seq, const float* __restrict__ att_mo, const float* __restrict__ att_om,
    int* __restrict__ off_seq, int* __restrict__ off_mo, int* __restrict__ off_om,
    float* __restrict__ al_seq, float* __restrict__ al_mo, float* __restrict__ al_om,
    int* __restrict__ bs_seq, int* __restrict__ bs_mo, int* __restrict__ bs_om) {
    const int ge = blockIdx.x * 256 + threadIdx.x;
    if (ge >= TOT_E) return;
    int s, d, pos;
    float f;
    float4 as, ad, aw;
    int* bs; float* abkt;
    if (ge < E_SEQ) {
        const int e = ge;
        s = seq_src[e]; d = seq_dst[e]; f = feat_seq[e];
        as = *reinterpret_cast<const float4*>(p_op + (size_t)s * 16 + 0);
        ad = *reinterpret_cast<const float4*>(p_op + (size_t)d * 16 + 4);
        aw = make_float4(att_seq[64], att_seq[ATT_DIM + 64], att_seq[2 * ATT_DIM + 64], att_seq[3 * ATT_DIM + 64]);
        pos = atomicAdd(&off_seq[d], 1);
        abkt = al_seq; bs = bs_seq;
    } else if (ge < E_SEQ + E_MO) {
        const int e = ge - E_SEQ;
        s = mo_src[e]; d = mo_dst[e]; f = feat_mo[e];
        as = *reinterpret_cast<const float4*>(p_mac + (size_t)s * 8 + 4);
        ad = *reinterpret_cast<const float4*>(p_op + (size_t)d * 16 + 12);
        aw = make_float4(att_mo[64], att_mo[ATT_DIM + 64], att_mo[2 * ATT_DIM + 64], att_mo[3 * ATT_DIM + 64]);
        pos = atomicAdd(&off_mo[d], 1);
        abkt = al_mo; bs = bs_mo;
    } else {
        const int e = ge - E_SEQ - E_MO;
        s = om_src[e]; d = om_dst[e]; f = feat_om[e];
        as = *reinterpret_cast<const float4*>(p_op + (size_t)s * 16 + 8);
        ad = *reinterpret_cast<const float4*>(p_mac + (size_t)d * 8 + 0);
        aw = make_float4(att_om[64], att_om[ATT_DIM + 64], att_om[2 * ATT_DIM + 64], att_om[3 * ATT_DIM + 64]);
        pos = atomicAdd(&off_om[d], 1);
        abkt = al_om; bs = bs_om;
    }
    const float sc[4] = {as.x + ad.x + f * aw.x, as.y + ad.y + f * aw.y,
                         as.z + ad.z + f * aw.z, as.w + ad.w + f * aw.w};
    float4 out;
    float* o = &out.x;
#pragma unroll
    for (int hh = 0; hh < 4; ++hh) {
        float v = sc[hh];
        v = (v >= 0.f) ? v : 0.2f * v;
        v = fminf(fmaxf(v, -20.f), 20.f);
        o[hh] = expf(v);
    }
    *reinterpret_cast<float4*>(abkt + (size_t)pos * HEADS) = out;
    bs[pos] = s;
}

// ---------------------------------------------------------------------------
// Gather. mac rows: one BLOCK per row (4 waves stride the ~150 edges, LDS
// combine, wave 0 finalizes). op rows: one WAVE per row (seq + mo segments).
// 2 cols per lane, bf16 z gathers, wave LN + ELU.
// ---------------------------------------------------------------------------
__device__ __forceinline__ void seg2(const int* __restrict__ bs, const float* __restrict__ al,
                                     const ushort_t* __restrict__ zb,
                                     int s0, int e0, int stride, int lane, int hd, int col2,
                                     float& num0, float& num1, float& den) {
    for (int base = s0; base < e0; base += stride) {
        int nn = e0 - base;
        if (nn > 64) nn = 64;
        int sidx = 0;
        if (base + lane < e0) sidx = bs[base + lane];
#pragma unroll 8
        for (int i = 0; i < nn; ++i) {
            const int s = __shfl(sidx, i);
            const float a = al[(size_t)(base + i) * HEADS + hd];
            const uint_t zz = *reinterpret_cast<const uint_t*>(zb + (size_t)s * OUT + col2);
            num0 = fmaf(a, __uint_as_float(zz << 16), num0);
            num1 = fmaf(a, __uint_as_float(zz & 0xffff0000u), num1);
            den += a;
        }
    }
}

__device__ __forceinline__ float2 ln_elu2(float x0, float x1, int lane,
                                          const float* __restrict__ g,
                                          const float* __restrict__ bb, int col2) {
    float s = x0 + x1;
#pragma unroll
    for (int m = 32; m >= 1; m >>= 1) s += __shfl_xor(s, m);
    const float mu = s * (1.0f / OUT);
    const float dx0 = x0 - mu, dx1 = x1 - mu;
    float q = dx0 * dx0 + dx1 * dx1;
#pragma unroll
    for (int m = 32; m >= 1; m >>= 1) q += __shfl_xor(q, m);
    const float r = rsqrtf(q * (1.0f / OUT) + LN_EPS);
    const float2 g2 = *reinterpret_cast<const float2*>(g + col2);
    const float2 b2 = *reinterpret_cast<const float2*>(bb + col2);
    float y0 = dx0 * r * g2.x + b2.x;
    float y1 = dx1 * r * g2.y + b2.y;
    y0 = (y0 > 0.f) ? y0 : expm1f(y0);
    y1 = (y1 > 0.f) ? y1 : expm1f(y1);
    return make_float2(y0, y1);
}

__global__ void k_gather(
    const int* __restrict__ bs_seq, const float* __restrict__ al_seq,
    const int* __restrict__ sta_seq, const int* __restrict__ off_seq,
    const int* __restrict__ bs_mo, const float* __restrict__ al_mo,
    const int* __restrict__ sta_mo, const int* __restrict__ off_mo,
    const int* __restrict__ bs_om, const float* __restrict__ al_om,
    const int* __restrict__ sta_om, const int* __restrict__ off_om,
    const ushort_t* __restrict__ zb_op, const ushort_t* __restrict__ zb_mac,
    const float* __restrict__ z_op, const float* __restrict__ z_mac,
    const float* __restrict__ g_op, const float* __restrict__ b_op,
    const float* __restrict__ g_mac, const float* __restrict__ b_mac,
    float* __restrict__ out_op, float* __restrict__ out_mac) {
    const int bid = blockIdx.x;
    const int t = threadIdx.x;
    const int w = t >> 6, lane = t & 63;
    const int hd = lane >> 4;
    const int col2 = lane * 2;
    __shared__ float nsh[4][OUT];
    __shared__ float dsh[4][HEADS];

    if (bid < N_MAC) {
        const int d = bid;
        const int s0 = sta_om[d], e0 = off_om[d];
        float num0 = 0.f, num1 = 0.f, den = 0.f;
        seg2(bs_om, al_om, zb_op, s0 + w * 64, e0, 256, lane, hd, col2, num0, num1, den);
        nsh[w][col2] = num0;
        nsh[w][col2 + 1] = num1;
        if ((lane & 15) == 0) dsh[w][hd] = den;
        __syncthreads();
        if (w == 0) {
            const float n0 = nsh[0][col2] + nsh[1][col2] + nsh[2][col2] + nsh[3][col2];
            const float n1 = nsh[0][col2 + 1] + nsh[1][col2 + 1] + nsh[2][col2 + 1] + nsh[3][col2 + 1];
            const float dt = dsh[0][hd] + dsh[1][hd] + dsh[2][hd] + dsh[3][hd];
            const float inv = 1.0f / (dt + EPS);
            const float2 zr = *reinterpret_cast<const float2*>(z_mac + (size_t)d * OUT + col2);
            const float2 o2 = ln_elu2(n0 * inv + zr.x, n1 * inv + zr.y, lane, g_mac, b_mac, col2);
            *reinterpret_cast<float2*>(out_mac + (size_t)d * OUT + col2) = o2;
        }
    } else {
        const int d = (bid - N_MAC) * 4 + w;
        if (d >= N_OP) return;
        float acc0 = 0.f, acc1 = 0.f;
        {
            float num0 = 0.f, num1 = 0.f, den = 0.f;
            seg2(bs_seq, al_seq, zb_op, sta_seq[d], off_seq[d], 64, lane, hd, col2, num0, num1, den);
            const float inv = 1.0f / (den + EPS);
            acc0 = num0 * inv; acc1 = num1 * inv;
        }
        {
            float num0 = 0.f, num1 = 0.f, den = 0.f;
            seg2(bs_mo, al_mo, zb_mac, sta_mo[d], off_mo[d], 64, lane, hd, col2, num0, num1, den);
            const float inv = 1.0f / (den + EPS);
            acc0 += num0 * inv; acc1 += num1 * inv;
        }
        const float2 zr = *reinterpret_cast<const float2*>(z_op + (size_t)d * OUT + col2);
        const float2 o2 = ln_elu2(acc0 + zr.x, acc1 + zr.y, lane, g_op, b_op, col2);
        *reinterpret_cast<float2*>(out_op + (size_t)d * OUT + col2) = o2;
    }
}

extern "C" void kernel_launch(void* const* d_in, const int* in_sizes, int n_in,
                              void* d_out, int out_size, void* d_ws, size_t ws_size,
                              hipStream_t stream) {
    const float* h_op      = (const float*)d_in[0];
    const float* h_mac     = (const float*)d_in[1];
    const int*   seq_src   = (const int*)d_in[2];
    const int*   seq_dst   = (const int*)d_in[3];
    const int*   om_src    = (const int*)d_in[4];
    const int*   om_dst    = (const int*)d_in[5];
    const int*   mo_src    = (const int*)d_in[6];
    const int*   mo_dst    = (const int*)d_in[7];
    const float* feat_seq  = (const float*)d_in[8];
    const float* feat_om   = (const float*)d_in[9];
    const float* feat_mo   = (const float*)d_in[10];
    const float* W_op_w    = (const float*)d_in[11];
    const float* W_op_b    = (const float*)d_in[12];
    const float* W_mac_w   = (const float*)d_in[13];
    const float* W_mac_b   = (const float*)d_in[14];
    const float* att_seq   = (const float*)d_in[15];
    const float* att_om    = (const float*)d_in[16];
    const float* att_mo    = (const float*)d_in[17];
    const float* ln_op_g   = (const float*)d_in[18];
    const float* ln_op_b   = (const float*)d_in[19];
    const float* ln_mac_g  = (const float*)d_in[20];
    const float* ln_mac_b  = (const float*)d_in[21];

    float* p = (float*)d_ws;
    float* z_op   = p; p += (size_t)N_OP * OUT;
    float* z_mac  = p; p += (size_t)N_MAC * OUT;
    float* p_op   = p; p += (size_t)N_OP * 16;
    float* p_mac  = p; p += (size_t)N_MAC * 8;
    float* al_seq = p; p += (size_t)E_SEQ * HEADS;
    float* al_mo  = p; p += (size_t)E_MO * HEADS;
    float* al_om  = p; p += (size_t)E_OM * HEADS;
    float* U_op   = p; p += 16 * IN_OP;
    float* c_op   = p; p += 16;
    float* U_mac  = p; p += 8 * IN_MAC;
    float* c_mac  = p; p += 16;
    ushort_t* zb_op  = (ushort_t*)p; p += (size_t)N_OP * OUT / 2;
    ushort_t* zb_mac = (ushort_t*)p; p += (size_t)N_MAC * OUT / 2;
    int* q = (int*)p;
    int* cnt_seq = q; q += N_OP;    // cnt_* + ctr contiguous, zeroed in k_prep
    int* cnt_mo  = q; q += N_OP;
    int* cnt_om  = q; q += N_MAC;
    int* ctr     = q; q += 4;
    int* sta_seq = q; q += N_OP;
    int* sta_mo  = q; q += N_OP;
    int* sta_om  = q; q += N_MAC;
    int* off_seq = q; q += N_OP;
    int* off_mo  = q; q += N_OP;
    int* off_om  = q; q += N_MAC;
    int* bs_seq  = q; q += E_SEQ;
    int* bs_mo   = q; q += E_MO;
    int* bs_om   = q; q += E_OM;

    float* out_op  = (float*)d_out;
    float* out_mac = (float*)d_out + (size_t)N_OP * OUT;

    k_prep<<<64, 256, 0, stream>>>(W_op_w, W_op_b, W_mac_w, W_mac_b,
                                   att_seq, att_om, att_mo,
                                   U_op, c_op, U_mac, c_mac, cnt_seq);

    k_phase1<<<GB_OP + GB_MAC + HB, 256, 0, stream>>>(
        h_op, W_op_w, W_op_b, h_mac, W_mac_w, W_mac_b,
        U_op, c_op, U_mac, c_mac,
        z_op, zb_op, z_mac, zb_mac, p_op, p_mac,
        seq_dst, mo_dst, om_dst, cnt_seq, cnt_mo, cnt_om);

    k_alloc<<<AB_SEQ + AB_MO + AB_OM, 256, 0, stream>>>(
        cnt_seq, sta_seq, off_seq, cnt_mo, sta_mo, off_mo, cnt_om, sta_om, off_om, ctr);

    k_fill_alpha<<<CNT_B, 256, 0, stream>>>(
        seq_src, seq_dst, feat_seq, mo_src, mo_dst, feat_mo, om_src, om_dst, feat_om,
        p_op, p_mac, att_seq, att_mo, att_om,
        off_seq, off_mo, off_om,
        al_seq, al_mo, al_om, bs_seq, bs_mo, bs_om);

    k_gather<<<N_MAC + (N_OP + 3) / 4, 256, 0, stream>>>(
        bs_seq, al_seq, sta_seq, off_seq,
        bs_mo, al_mo, sta_mo, off_mo,
        bs_om, al_om, sta_om, off_om,
        zb_op, zb_mac, z_op, z_mac,
        ln_op_g, ln_op_b, ln_mac_g, ln_mac_b,
        out_op, out_mac);
}

// Round 7
// 243.138 us; speedup vs baseline: 1.6762x; 1.0230x over previous
//
#include <hip/hip_runtime.h>

#define N_OP   50000
#define N_MAC  2000
#define IN_OP  64
#define IN_MAC 32
#define OUT    128
#define HEADS  4
#define DK     32
#define ATT_DIM 65
#define E_SEQ  150000
#define E_OM   300000
#define E_MO   300000
#define TOT_E  (E_SEQ + E_MO + E_OM)
#define EPS    1e-6f
#define LN_EPS 1e-5f

// phase1 grid regions (blocks of 256 = 4 waves)
#define BA 512    // op z-GEMM: 2048 waves (1024 per column-half)
#define BB 16     // mac z-GEMM: 64 waves (32 per half)
#define BC 128    // op projections: 512 waves
#define BD 4      // mac projections: 16 waves
#define BE 128    // histograms (grid-stride)
#define CNT_B   ((TOT_E + 255) / 256)

#define AB_SEQ  ((N_OP + 255) / 256)
#define AB_MO   ((N_OP + 255) / 256)
#define AB_OM   ((N_MAC + 255) / 256)

typedef unsigned short ushort_t;
typedef unsigned int   uint_t;

__device__ __forceinline__ ushort_t f32_to_bf16_rtne(float f) {
    uint_t u = __float_as_uint(f);
    u += 0x7FFFu + ((u >> 16) & 1u);
    return (ushort_t)(u >> 16);
}

// ---------------------------------------------------------------------------
// Prep: block 0 folds attention through W (U = att o W, c = att o b) and
// transposes W -> WT (so GEMM waves load W columns coalesced);
// blocks >= 1 zero the count/ctr arrays.
// ---------------------------------------------------------------------------
__global__ void k_prep(const float* __restrict__ W_op, const float* __restrict__ b_op,
                       const float* __restrict__ W_mac, const float* __restrict__ b_mac,
                       const float* __restrict__ att_seq, const float* __restrict__ att_om,
                       const float* __restrict__ att_mo,
                       float* __restrict__ U_op, float* __restrict__ c_op,
                       float* __restrict__ U_mac, float* __restrict__ c_mac,
                       float* __restrict__ WT_op, float* __restrict__ WT_mac,
                       int* __restrict__ zero_base) {
    const int t = threadIdx.x;
    if (blockIdx.x == 0) {
        // U_op row j = pr*4+hd: pr0=seq_src, pr1=seq_dst, pr2=om_src, pr3=mo_dst
        for (int idx = t; idx < 16 * IN_OP; idx += 256) {
            const int j = idx >> 6, k = idx & 63;
            const int hd = j & 3, pr = j >> 2;
            const float* att = (pr <= 1) ? att_seq : (pr == 2 ? att_om : att_mo);
            const int off = (pr == 1 || pr == 3) ? 32 : 0;
            float s = 0.f;
            for (int l = 0; l < 32; ++l)
                s += att[hd * ATT_DIM + off + l] * W_op[(hd * 32 + l) * IN_OP + k];
            U_op[idx] = s;
        }
        if (t < 16) {
            const int hd = t & 3, pr = t >> 2;
            const float* att = (pr <= 1) ? att_seq : (pr == 2 ? att_om : att_mo);
            const int off = (pr == 1 || pr == 3) ? 32 : 0;
            float s = 0.f;
            for (int l = 0; l < 32; ++l) s += att[hd * ATT_DIM + off + l] * b_op[hd * 32 + l];
            c_op[t] = s;
        }
        // U_mac row j: pr0=om_dst(att_om[32:64]), pr1=mo_src(att_mo[0:32])
        for (int idx = t; idx < 8 * IN_MAC; idx += 256) {
            const int j = idx >> 5, k = idx & 31;
            const int hd = j & 3, pr = j >> 2;
            const float* att = (pr == 0) ? att_om : att_mo;
            const int off = (pr == 0) ? 32 : 0;
            float s = 0.f;
            for (int l = 0; l < 32; ++l)
                s += att[hd * ATT_DIM + off + l] * W_mac[(hd * 32 + l) * IN_MAC + k];
            U_mac[idx] = s;
        }
        if (t < 8) {
            const int hd = t & 3, pr = t >> 2;
            const float* att = (pr == 0) ? att_om : att_mo;
            const int off = (pr == 0) ? 32 : 0;
            float s = 0.f;
            for (int l = 0; l < 32; ++l) s += att[hd * ATT_DIM + off + l] * b_mac[hd * 32 + l];
            c_mac[t] = s;
        }
        // transposes: WT[k][c] = W[c][k]
        for (int idx = t; idx < IN_OP * OUT; idx += 256) {
            const int k = idx >> 7, c = idx & 127;
            WT_op[idx] = W_op[c * IN_OP + k];
        }
        for (int idx = t; idx < IN_MAC * OUT; idx += 256) {
            const int k = idx >> 7, c = idx & 127;
            WT_mac[idx] = W_mac[c * IN_MAC + k];
        }
    } else {
        const int n = 2 * N_OP + N_MAC + 4;
        for (int i = (blockIdx.x - 1) * 256 + t; i < n; i += 63 * 256)
            zero_base[i] = 0;
    }
}

// ---------------------------------------------------------------------------
// Phase 1 — no LDS, no barriers. Per wave, h[row] is WAVE-UNIFORM
// (lane = output column), so h row loads scalarize to s_load broadcasts;
// W^T column slice sits in 64 VGPRs loaded once per wave.
// [A] op z-GEMM | [B] mac z-GEMM | [C] op proj | [D] mac proj | [E] histo.
// __launch_bounds__(256,4): VGPR cap 128 (need ~85; avoids both the R5
// default-cap-64 spill and the R6 128-reg occupancy collapse).
// ---------------------------------------------------------------------------
__global__ void __launch_bounds__(256, 4) k_phase1(
    const float* __restrict__ h_op, const float* __restrict__ WT_op, const float* __restrict__ b_op,
    const float* __restrict__ h_mac, const float* __restrict__ WT_mac, const float* __restrict__ b_mac,
    const float* __restrict__ U_op, const float* __restrict__ c_op,
    const float* __restrict__ U_mac, const float* __restrict__ c_mac,
    float* __restrict__ z_op, ushort_t* __restrict__ zb_op,
    float* __restrict__ z_mac, ushort_t* __restrict__ zb_mac,
    float* __restrict__ p_op, float* __restrict__ p_mac,
    const int* __restrict__ seq_dst, const int* __restrict__ mo_dst, const int* __restrict__ om_dst,
    int* __restrict__ cnt_seq, int* __restrict__ cnt_mo, int* __restrict__ cnt_om) {
    const int bid = blockIdx.x;
    const int t = threadIdx.x;
    const int w = t >> 6, lane = t & 63;

    if (bid < BA) {
        // ---- [A] op z: wave owns one 64-col half; lane = column ----
        const int wg = bid * 4 + w;            // 0..2047
        const int half = wg >> 10, wid = wg & 1023;
        const int cbase = half * 64 + lane;
        float wreg[IN_OP];
#pragma unroll
        for (int k = 0; k < IN_OP; ++k) wreg[k] = WT_op[k * OUT + cbase];
        const float bias = b_op[cbase];
        for (int r = wid; r < N_OP; r += 1024) {
            const int row = __builtin_amdgcn_readfirstlane(r);
            const float* hr = h_op + (size_t)row * IN_OP;
            float a0 = 0.f, a1 = 0.f, a2 = 0.f, a3 = 0.f;
#pragma unroll
            for (int k = 0; k < IN_OP; k += 4) {
                a0 = fmaf(hr[k + 0], wreg[k + 0], a0);
                a1 = fmaf(hr[k + 1], wreg[k + 1], a1);
                a2 = fmaf(hr[k + 2], wreg[k + 2], a2);
                a3 = fmaf(hr[k + 3], wreg[k + 3], a3);
            }
            const float acc = bias + ((a0 + a1) + (a2 + a3));
            const size_t o = (size_t)row * OUT + cbase;
            z_op[o] = acc;
            zb_op[o] = f32_to_bf16_rtne(acc);
        }
    } else if (bid < BA + BB) {
        // ---- [B] mac z ----
        const int wg = (bid - BA) * 4 + w;     // 0..63
        const int half = wg >> 5, wid = wg & 31;
        const int cbase = half * 64 + lane;
        float wreg[IN_MAC];
#pragma unroll
        for (int k = 0; k < IN_MAC; ++k) wreg[k] = WT_mac[k * OUT + cbase];
        const float bias = b_mac[cbase];
        for (int r = wid; r < N_MAC; r += 32) {
            const int row = __builtin_amdgcn_readfirstlane(r);
            const float* hr = h_mac + (size_t)row * IN_MAC;
            float a0 = 0.f, a1 = 0.f, a2 = 0.f, a3 = 0.f;
#pragma unroll
            for (int k = 0; k < IN_MAC; k += 4) {
                a0 = fmaf(hr[k + 0], wreg[k + 0], a0);
                a1 = fmaf(hr[k + 1], wreg[k + 1], a1);
                a2 = fmaf(hr[k + 2], wreg[k + 2], a2);
                a3 = fmaf(hr[k + 3], wreg[k + 3], a3);
            }
            const float acc = bias + ((a0 + a1) + (a2 + a3));
            const size_t o = (size_t)row * OUT + cbase;
            z_mac[o] = acc;
            zb_mac[o] = f32_to_bf16_rtne(acc);
        }
    } else if (bid < BA + BB + BC) {
        // ---- [C] op projections: lane = (kg,j); k split 4 ways, shfl reduce ----
        const int wg = (bid - BA - BB) * 4 + w;   // 0..511
        const int j = lane & 15, kg = lane >> 4;
        float u[16];
#pragma unroll
        for (int i = 0; i < 16; ++i) u[i] = U_op[j * IN_OP + kg * 16 + i];
        const float cj = c_op[j];
        for (int r = wg; r < N_OP; r += BC * 4) {
            const int row = __builtin_amdgcn_readfirstlane(r);
            const float* hr = h_op + (size_t)row * IN_OP + kg * 16;
            float p0 = 0.f, p1 = 0.f, p2 = 0.f, p3 = 0.f;
#pragma unroll
            for (int i = 0; i < 16; i += 4) {
                p0 = fmaf(hr[i + 0], u[i + 0], p0);
                p1 = fmaf(hr[i + 1], u[i + 1], p1);
                p2 = fmaf(hr[i + 2], u[i + 2], p2);
                p3 = fmaf(hr[i + 3], u[i + 3], p3);
            }
            float v = (p0 + p1) + (p2 + p3);
            v += __shfl_xor(v, 16);
            v += __shfl_xor(v, 32);
            if (kg == 0) p_op[(size_t)row * 16 + j] = cj + v;
        }
    } else if (bid < BA + BB + BC + BD) {
        // ---- [D] mac projections: lane = (kg,j), 8 k-groups of 4 ----
        const int wg = (bid - BA - BB - BC) * 4 + w;  // 0..15
        const int j = lane & 7, kg = lane >> 3;
        float u[4];
#pragma unroll
        for (int i = 0; i < 4; ++i) u[i] = U_mac[j * IN_MAC + kg * 4 + i];
        const float cj = c_mac[j];
        for (int r = wg; r < N_MAC; r += BD * 4) {
            const int row = __builtin_amdgcn_readfirstlane(r);
            const float* hr = h_mac + (size_t)row * IN_MAC + kg * 4;
            float v = 0.f;
#pragma unroll
            for (int i = 0; i < 4; ++i) v = fmaf(hr[i], u[i], v);
            v += __shfl_xor(v, 8);
            v += __shfl_xor(v, 16);
            v += __shfl_xor(v, 32);
            if (kg == 0) p_mac[(size_t)row * 8 + j] = cj + v;
        }
    } else {
        // ---- [E] degree histograms, grid-stride ----
        const int b2 = bid - BA - BB - BC - BD;
        for (int ge = b2 * 256 + t; ge < TOT_E; ge += BE * 256) {
            if (ge < E_SEQ) atomicAdd(&cnt_seq[seq_dst[ge]], 1);
            else if (ge < E_SEQ + E_MO) atomicAdd(&cnt_mo[mo_dst[ge - E_SEQ]], 1);
            else atomicAdd(&cnt_om[om_dst[ge - E_SEQ - E_MO]], 1);
        }
    }
}

// ---------------------------------------------------------------------------
// Range allocation: per-wave scan of counts + one atomicAdd per wave.
// ---------------------------------------------------------------------------
__global__ void k_alloc(const int* __restrict__ cnt_seq, int* __restrict__ sta_seq, int* __restrict__ off_seq,
                        const int* __restrict__ cnt_mo,  int* __restrict__ sta_mo,  int* __restrict__ off_mo,
                        const int* __restrict__ cnt_om,  int* __restrict__ sta_om,  int* __restrict__ off_om,
                        int* __restrict__ ctr) {
    const int b = blockIdx.x, t = threadIdx.x;
    const int* cnt; int* sta; int* off; int n, g, lb;
    if (b < AB_SEQ)             { cnt = cnt_seq; sta = sta_seq; off = off_seq; n = N_OP;  g = 0; lb = b; }
    else if (b < AB_SEQ + AB_MO){ cnt = cnt_mo;  sta = sta_mo;  off = off_mo;  n = N_OP;  g = 1; lb = b - AB_SEQ; }
    else                        { cnt = cnt_om;  sta = sta_om;  off = off_om;  n = N_MAC; g = 2; lb = b - AB_SEQ - AB_MO; }
    const int d = lb * 256 + t;
    const int lane = t & 63;
    const int v = (d < n) ? cnt[d] : 0;
    int x = v;
#pragma unroll
    for (int m = 1; m < 64; m <<= 1) {
        int y = __shfl_up(x, m);
        if (lane >= m) x += y;
    }
    int base = 0;
    if (lane == 63) base = atomicAdd(&ctr[g], x);
    base = __shfl(base, 63);
    if (d < n) {
        const int s = base + x - v;
        sta[d] = s;
        off[d] = s;
    }
}

// ---------------------------------------------------------------------------
// Fill + alpha (all 3 graphs), written in bucket order.
// ---------------------------------------------------------------------------
__global__ void k_fill_alpha(
    const int* __restrict__ seq_src, const int* __restrict__ seq_dst, const float* __restrict__ feat_seq,
    const int* __restrict__ mo_src,  const int* __restrict__ mo_dst,  const float* __restrict__ feat_mo,
    const int* __restrict__ om_src,  const int* __restrict__ om_dst,  const float* __restrict__ feat_om,
    const float* __restrict__ p_op, const float* __restrict__ p_mac,
    const float* __restrict__ att_seq, const float* __restrict__ att_mo, const float* __restrict__ att_om,
    int* __restrict__ off_seq, int* __restrict__ off_mo, int* __restrict__ off_om,
    float* __restrict__ al_seq, float* __restrict__ al_mo, float* __restrict__ al_om,
    int* __restrict__ bs_seq, int* __restrict__ bs_mo, int* __restrict__ bs_om) {
    const int ge = blockIdx.x * 256 + threadIdx.x;
    if (ge >= TOT_E) return;
    int s, d, pos;
    float f;
    float4 as, ad, aw;
    int* bs; float* abkt;
    if (ge < E_SEQ) {
        const int e = ge;
        s = seq_src[e]; d = seq_dst[e]; f = feat_seq[e];
        as = *reinterpret_cast<const float4*>(p_op + (size_t)s * 16 + 0);
        ad = *reinterpret_cast<const float4*>(p_op + (size_t)d * 16 + 4);
        aw = make_float4(att_seq[64], att_seq[ATT_DIM + 64], att_seq[2 * ATT_DIM + 64], att_seq[3 * ATT_DIM + 64]);
        pos = atomicAdd(&off_seq[d], 1);
        abkt = al_seq; bs = bs_seq;
    } else if (ge < E_SEQ + E_MO) {
        const int e = ge - E_SEQ;
        s = mo_src[e]; d = mo_dst[e]; f = feat_mo[e];
        as = *reinterpret_cast<const float4*>(p_mac + (size_t)s * 8 + 4);
        ad = *reinterpret_cast<const float4*>(p_op + (size_t)d * 16 + 12);
        aw = make_float4(att_mo[64], att_mo[ATT_DIM + 64], att_mo[2 * ATT_DIM + 64], att_mo[3 * ATT_DIM + 64]);
        pos = atomicAdd(&off_mo[d], 1);
        abkt = al_mo; bs = bs_mo;
    } else {
        const int e = ge - E_SEQ - E_MO;
        s = om_src[e]; d = om_dst[e]; f = feat_om[e];
        as = *reinterpret_cast<const float4*>(p_op + (size_t)s * 16 + 8);
        ad = *reinterpret_cast<const float4*>(p_mac + (size_t)d * 8 + 0);
        aw = make_float4(att_om[64], att_om[ATT_DIM + 64], att_om[2 * ATT_DIM + 64], att_om[3 * ATT_DIM + 64]);
        pos = atomicAdd(&off_om[d], 1);
        abkt = al_om; bs = bs_om;
    }
    const float sc[4] = {as.x + ad.x + f * aw.x, as.y + ad.y + f * aw.y,
                         as.z + ad.z + f * aw.z, as.w + ad.w + f * aw.w};
    float4 out;
    float* o = &out.x;
#pragma unroll
    for (int hh = 0; hh < 4; ++hh) {
        float v = sc[hh];
        v = (v >= 0.f) ? v : 0.2f * v;
        v = fminf(fmaxf(v, -20.f), 20.f);
        o[hh] = expf(v);
    }
    *reinterpret_cast<float4*>(abkt + (size_t)pos * HEADS) = out;
    bs[pos] = s;
}

// ---------------------------------------------------------------------------
// Gather. mac rows: one BLOCK per row (4 waves stride the ~150 edges, LDS
// combine, wave 0 finalizes). op rows: one WAVE per row (seq + mo segments).
// 2 cols per lane, bf16 z gathers, wave LN + ELU.
// ---------------------------------------------------------------------------
__device__ __forceinline__ void seg2(const int* __restrict__ bs, const float* __restrict__ al,
                                     const ushort_t* __restrict__ zb,
                                     int s0, int e0, int stride, int lane, int hd, int col2,
                                     float& num0, float& num1, float& den) {
    for (int base = s0; base < e0; base += stride) {
        int nn = e0 - base;
        if (nn > 64) nn = 64;
        int sidx = 0;
        if (base + lane < e0) sidx = bs[base + lane];
#pragma unroll 8
        for (int i = 0; i < nn; ++i) {
            const int s = __shfl(sidx, i);
            const float a = al[(size_t)(base + i) * HEADS + hd];
            const uint_t zz = *reinterpret_cast<const uint_t*>(zb + (size_t)s * OUT + col2);
            num0 = fmaf(a, __uint_as_float(zz << 16), num0);
            num1 = fmaf(a, __uint_as_float(zz & 0xffff0000u), num1);
            den += a;
        }
    }
}

__device__ __forceinline__ float2 ln_elu2(float x0, float x1, int lane,
                                          const float* __restrict__ g,
                                          const float* __restrict__ bb, int col2) {
    float s = x0 + x1;
#pragma unroll
    for (int m = 32; m >= 1; m >>= 1) s += __shfl_xor(s, m);
    const float mu = s * (1.0f / OUT);
    const float dx0 = x0 - mu, dx1 = x1 - mu;
    float q = dx0 * dx0 + dx1 * dx1;
#pragma unroll
    for (int m = 32; m >= 1; m >>= 1) q += __shfl_xor(q, m);
    const float r = rsqrtf(q * (1.0f / OUT) + LN_EPS);
    const float2 g2 = *reinterpret_cast<const float2*>(g + col2);
    const float2 b2 = *reinterpret_cast<const float2*>(bb + col2);
    float y0 = dx0 * r * g2.x + b2.x;
    float y1 = dx1 * r * g2.y + b2.y;
    y0 = (y0 > 0.f) ? y0 : expm1f(y0);
    y1 = (y1 > 0.f) ? y1 : expm1f(y1);
    return make_float2(y0, y1);
}

__global__ void k_gather(
    const int* __restrict__ bs_seq, const float* __restrict__ al_seq,
    const int* __restrict__ sta_seq, const int* __restrict__ off_seq,
    const int* __restrict__ bs_mo, const float* __restrict__ al_mo,
    const int* __restrict__ sta_mo, const int* __restrict__ off_mo,
    const int* __restrict__ bs_om, const float* __restrict__ al_om,
    const int* __restrict__ sta_om, const int* __restrict__ off_om,
    const ushort_t* __restrict__ zb_op, const ushort_t* __restrict__ zb_mac,
    const float* __restrict__ z_op, const float* __restrict__ z_mac,
    const float* __restrict__ g_op, const float* __restrict__ b_op,
    const float* __restrict__ g_mac, const float* __restrict__ b_mac,
    float* __restrict__ out_op, float* __restrict__ out_mac) {
    const int bid = blockIdx.x;
    const int t = threadIdx.x;
    const int w = t >> 6, lane = t & 63;
    const int hd = lane >> 4;
    const int col2 = lane * 2;
    __shared__ float nsh[4][OUT];
    __shared__ float dsh[4][HEADS];

    if (bid < N_MAC) {
        const int d = bid;
        const int s0 = sta_om[d], e0 = off_om[d];
        float num0 = 0.f, num1 = 0.f, den = 0.f;
        seg2(bs_om, al_om, zb_op, s0 + w * 64, e0, 256, lane, hd, col2, num0, num1, den);
        nsh[w][col2] = num0;
        nsh[w][col2 + 1] = num1;
        if ((lane & 15) == 0) dsh[w][hd] = den;
        __syncthreads();
        if (w == 0) {
            const float n0 = nsh[0][col2] + nsh[1][col2] + nsh[2][col2] + nsh[3][col2];
            const float n1 = nsh[0][col2 + 1] + nsh[1][col2 + 1] + nsh[2][col2 + 1] + nsh[3][col2 + 1];
            const float dt = dsh[0][hd] + dsh[1][hd] + dsh[2][hd] + dsh[3][hd];
            const float inv = 1.0f / (dt + EPS);
            const float2 zr = *reinterpret_cast<const float2*>(z_mac + (size_t)d * OUT + col2);
            const float2 o2 = ln_elu2(n0 * inv + zr.x, n1 * inv + zr.y, lane, g_mac, b_mac, col2);
            *reinterpret_cast<float2*>(out_mac + (size_t)d * OUT + col2) = o2;
        }
    } else {
        const int d = (bid - N_MAC) * 4 + w;
        if (d >= N_OP) return;
        float acc0 = 0.f, acc1 = 0.f;
        {
            float num0 = 0.f, num1 = 0.f, den = 0.f;
            seg2(bs_seq, al_seq, zb_op, sta_seq[d], off_seq[d], 64, lane, hd, col2, num0, num1, den);
            const float inv = 1.0f / (den + EPS);
            acc0 = num0 * inv; acc1 = num1 * inv;
        }
        {
            float num0 = 0.f, num1 = 0.f, den = 0.f;
            seg2(bs_mo, al_mo, zb_mac, sta_mo[d], off_mo[d], 64, lane, hd, col2, num0, num1, den);
            const float inv = 1.0f / (den + EPS);
            acc0 += num0 * inv; acc1 += num1 * inv;
        }
        const float2 zr = *reinterpret_cast<const float2*>(z_op + (size_t)d * OUT + col2);
        const float2 o2 = ln_elu2(acc0 + zr.x, acc1 + zr.y, lane, g_op, b_op, col2);
        *reinterpret_cast<float2*>(out_op + (size_t)d * OUT + col2) = o2;
    }
}

extern "C" void kernel_launch(void* const* d_in, const int* in_sizes, int n_in,
                              void* d_out, int out_size, void* d_ws, size_t ws_size,
                              hipStream_t stream) {
    const float* h_op      = (const float*)d_in[0];
    const float* h_mac     = (const float*)d_in[1];
    const int*   seq_src   = (const int*)d_in[2];
    const int*   seq_dst   = (const int*)d_in[3];
    const int*   om_src    = (const int*)d_in[4];
    const int*   om_dst    = (const int*)d_in[5];
    const int*   mo_src    = (const int*)d_in[6];
    const int*   mo_dst    = (const int*)d_in[7];
    const float* feat_seq  = (const float*)d_in[8];
    const float* feat_om   = (const float*)d_in[9];
    const float* feat_mo   = (const float*)d_in[10];
    const float* W_op_w    = (const float*)d_in[11];
    const float* W_op_b    = (const float*)d_in[12];
    const float* W_mac_w   = (const float*)d_in[13];
    const float* W_mac_b   = (const float*)d_in[14];
    const float* att_seq   = (const float*)d_in[15];
    const float* att_om    = (const float*)d_in[16];
    const float* att_mo    = (const float*)d_in[17];
    const float* ln_op_g   = (const float*)d_in[18];
    const float* ln_op_b   = (const float*)d_in[19];
    const float* ln_mac_g  = (const float*)d_in[20];
    const float* ln_mac_b  = (const float*)d_in[21];

    float* p = (float*)d_ws;
    float* z_op   = p; p += (size_t)N_OP * OUT;
    float* z_mac  = p; p += (size_t)N_MAC * OUT;
    float* p_op   = p; p += (size_t)N_OP * 16;
    float* p_mac  = p; p += (size_t)N_MAC * 8;
    float* al_seq = p; p += (size_t)E_SEQ * HEADS;
    float* al_mo  = p; p += (size_t)E_MO * HEADS;
    float* al_om  = p; p += (size_t)E_OM * HEADS;
    float* U_op   = p; p += 16 * IN_OP;
    float* c_op   = p; p += 16;
    float* U_mac  = p; p += 8 * IN_MAC;
    float* c_mac  = p; p += 16;
    float* WT_op  = p; p += IN_OP * OUT;
    float* WT_mac = p; p += IN_MAC * OUT;
    ushort_t* zb_op  = (ushort_t*)p; p += (size_t)N_OP * OUT / 2;
    ushort_t* zb_mac = (ushort_t*)p; p += (size_t)N_MAC * OUT / 2;
    int* q = (int*)p;
    int* cnt_seq = q; q += N_OP;    // cnt_* + ctr contiguous, zeroed in k_prep
    int* cnt_mo  = q; q += N_OP;
    int* cnt_om  = q; q += N_MAC;
    int* ctr     = q; q += 4;
    int* sta_seq = q; q += N_OP;
    int* sta_mo  = q; q += N_OP;
    int* sta_om  = q; q += N_MAC;
    int* off_seq = q; q += N_OP;
    int* off_mo  = q; q += N_OP;
    int* off_om  = q; q += N_MAC;
    int* bs_seq  = q; q += E_SEQ;
    int* bs_mo   = q; q += E_MO;
    int* bs_om   = q; q += E_OM;

    float* out_op  = (float*)d_out;
    float* out_mac = (float*)d_out + (size_t)N_OP * OUT;

    k_prep<<<64, 256, 0, stream>>>(W_op_w, W_op_b, W_mac_w, W_mac_b,
                                   att_seq, att_om, att_mo,
                                   U_op, c_op, U_mac, c_mac, WT_op, WT_mac, cnt_seq);

    k_phase1<<<BA + BB + BC + BD + BE, 256, 0, stream>>>(
        h_op, WT_op, W_op_b, h_mac, WT_mac, W_mac_b,
        U_op, c_op, U_mac, c_mac,
        z_op, zb_op, z_mac, zb_mac, p_op, p_mac,
        seq_dst, mo_dst, om_dst, cnt_seq, cnt_mo, cnt_om);

    k_alloc<<<AB_SEQ + AB_MO + AB_OM, 256, 0, stream>>>(
        cnt_seq, sta_seq, off_seq, cnt_mo, sta_mo, off_mo, cnt_om, sta_om, off_om, ctr);

    k_fill_alpha<<<CNT_B, 256, 0, stream>>>(
        seq_src, seq_dst, feat_seq, mo_src, mo_dst, feat_mo, om_src, om_dst, feat_om,
        p_op, p_mac, att_seq, att_mo, att_om,
        off_seq, off_mo, off_om,
        al_seq, al_mo, al_om, bs_seq, bs_mo, bs_om);

    k_gather<<<N_MAC + (N_OP + 3) / 4, 256, 0, stream>>>(
        bs_seq, al_seq, sta_seq, off_seq,
        bs_mo, al_mo, sta_mo, off_mo,
        bs_om, al_om, sta_om, off_om,
        zb_op, zb_mac, z_op, z_mac,
        ln_op_g, ln_op_b, ln_mac_g, ln_mac_b,
        out_op, out_mac);
}